// Round 3
// baseline (747.138 us; speedup 1.0000x reference)
//
#include <hip/hip_runtime.h>
#include <hip/hip_bf16.h>

typedef __attribute__((ext_vector_type(8))) short short8;
typedef __attribute__((ext_vector_type(4))) float floatx4;

#define B_ROWS 4096
#define N_COLS 8192
#define K_DIM  4096
#define INV_T  10.0f
#define NT     128   // K tiles of BK=32

// round-half-up fp32 -> bf16 pair pack
__device__ __forceinline__ unsigned pack2bf16(float a, float b) {
    unsigned lo = (__float_as_uint(a) + 0x8000u) >> 16;
    unsigned hi = (__float_as_uint(b) + 0x8000u) & 0xFFFF0000u;
    return lo | hi;
}

// async global->LDS, 16B per lane, LDS dest = wave-uniform base + lane*16
__device__ __forceinline__ void gload_lds16(const void* g, void* l) {
    __builtin_amdgcn_global_load_lds(
        (const __attribute__((address_space(1))) void*)g,
        (__attribute__((address_space(3))) void*)l,
        16, 0, 0);
}

// ---------------------------------------------------------------------------
// K0: convert im,s -> bf16 in ws; fused diag computation. (unchanged)
// ---------------------------------------------------------------------------
__global__ __launch_bounds__(256) void convert_diag_kernel(
    const float* __restrict__ im, const float* __restrict__ s,
    const float* __restrict__ sims,
    unsigned short* __restrict__ im_b, unsigned short* __restrict__ s_b,
    float* __restrict__ diag)
{
    const int row = blockIdx.x;                       // 0..8191
    const float4* srow = (const float4*)(s + (size_t)row * K_DIM);
    uint4* sb = (uint4*)(s_b + (size_t)row * K_DIM);
    const bool has_im = row < B_ROWS;
    const float4* arow = (const float4*)(im + (size_t)row * K_DIM);
    uint4* ab = (uint4*)(im_b + (size_t)row * K_DIM);

    float sum = 0.f;
    for (int i = threadIdx.x; i < K_DIM / 8; i += 256) {
        float4 y0 = srow[2 * i], y1 = srow[2 * i + 1];
        sb[i] = make_uint4(pack2bf16(y0.x, y0.y), pack2bf16(y0.z, y0.w),
                           pack2bf16(y1.x, y1.y), pack2bf16(y1.z, y1.w));
        if (has_im) {
            float4 x0 = arow[2 * i], x1 = arow[2 * i + 1];
            ab[i] = make_uint4(pack2bf16(x0.x, x0.y), pack2bf16(x0.z, x0.w),
                               pack2bf16(x1.x, x1.y), pack2bf16(x1.z, x1.w));
            sum += x0.x * y0.x + x0.y * y0.y + x0.z * y0.z + x0.w * y0.w;
            sum += x1.x * y1.x + x1.y * y1.y + x1.z * y1.z + x1.w * y1.w;
        }
    }
    if (has_im) {
        #pragma unroll
        for (int off = 1; off < 64; off <<= 1) sum += __shfl_xor(sum, off, 64);
        __shared__ float wsum[4];
        const int lane = threadIdx.x & 63, wid = threadIdx.x >> 6;
        if (lane == 0) wsum[wid] = sum;
        __syncthreads();
        if (threadIdx.x == 0) {
            float tot = wsum[0] + wsum[1] + wsum[2] + wsum[3];
            diag[row] = 0.5f * sims[(size_t)row * N_COLS + row] + 0.5f * tot;
        }
    }
}

// ---------------------------------------------------------------------------
// K1: 256x256 tile, BK=32, 8 waves (2Mx4N), triple-buffered LDS staging,
// counted-vmcnt phase pipeline, fused loss epilogue.
//
// Block->tile mapping (under test, L2/L3 locality):
//   Concurrent set (256 blocks, 1 block/CU) covers a 16it x 16jt SQUARE:
//   all A (32 MB) + half of B (32 MB) resident in L3. Each XCD (bid%8,
//   round-robin dispatch) gets a compact 8it x 4jt sub-region -> per-K-step
//   hot slices = (8+4) x 16 KB = 192 KB -> L2-served after first reader.
//   Old mapping streamed 64 MB of B per it-row through each 4 MB L2
//   (FETCH_SIZE 794 MB, ~3.5x ideal; MfmaUtil 24%).
//
// Buffers: tile t reads buf t%3; prefetch of tile t+2 goes to buf (t+2)%3
//   (drained at boundary barrier of t -> no write-while-read hazard).
// vmcnt: 4 staging loads/thread/tile. Boundary waits vmcnt(4): tile t landed,
//   tile t+1's 4 stay in flight (never drains to 0 in the loop).
// Swizzle (both sides): LDS slot s of row r holds k-group s ^ ((r>>1)&3);
//   staging pre-swizzles per-lane GLOBAL addr, LDS dest linear; read quad =
//   4*(row&1) + (q ^ ((row>>1)&3)) -> 8 quads x 2 lanes = conflict-free.
// ---------------------------------------------------------------------------
__global__ __launch_bounds__(512, 2) void gemm_loss_256_kernel(
    const unsigned short* __restrict__ im_b, const unsigned short* __restrict__ s_b,
    const float* __restrict__ sims, const float* __restrict__ diag,
    float* __restrict__ pi2t_m, float* __restrict__ pi2t_l,
    float* __restrict__ pt2i_m, float* __restrict__ pt2i_l)
{
    const int bid  = blockIdx.x;
    const int half = bid >> 8;           // 0: jt 0..15, 1: jt 16..31
    const int xcd  = bid & 7;            // round-robin dispatch => XCD id
    const int l    = (bid >> 3) & 31;    // 32 blocks per XCD per half
    const int it   = (xcd >> 2) * 8 + (l & 7);           // 0..15
    const int jt   = half * 16 + (xcd & 3) * 4 + (l >> 3); // 0..31
    const int tid = threadIdx.x;
    const int wid = tid >> 6, lane = tid & 63;
    const int wr = wid >> 2, wc = wid & 3;         // wave grid 2 x 4
    const int q = lane >> 4, cl = lane & 15;

    __shared__ __align__(16) unsigned short As[3][256 * 32];  // 48 KB
    __shared__ __align__(16) unsigned short Bs[3][256 * 32];  // 48 KB
    __shared__ float sm_m[4][256], sm_l[4][256];              // 8 KB
    __shared__ float sc_m[2][256], sc_l[2][256];              // 4 KB

    // staging source (pre-swizzled global addr); idx = call*512 + tid,
    // row = idx>>2, slot = idx&3, src k-slot = slot ^ ((idx>>3)&3)
    const int srow = tid >> 2;
    const int skel = ((tid & 3) ^ ((tid >> 3) & 3)) * 8;
    const unsigned short* gA0 = im_b + (size_t)(it * 256 + srow) * K_DIM + skel;
    const unsigned short* gA1 = gA0 + (size_t)128 * K_DIM;
    const unsigned short* gB0 = s_b + (size_t)(jt * 256 + srow) * K_DIM + skel;
    const unsigned short* gB1 = gB0 + (size_t)128 * K_DIM;
    const int ld0 = wid * 512;          // wave-uniform LDS element offsets
    const int ld1 = 4096 + wid * 512;

    // read-side swizzled fragment offsets (elements), invariant over K
    const int swz = (q ^ ((cl >> 1) & 3)) * 8;
    int roffA[4], roffB[4];
    #pragma unroll
    for (int t = 0; t < 4; ++t) {
        roffA[t] = (wr * 128 + t * 16 + cl) * 32 + swz;
        roffB[t] = (wc * 64  + t * 16 + cl) * 32 + swz;
    }

    floatx4 acc[8][4];
    #pragma unroll
    for (int i = 0; i < 8; ++i)
        #pragma unroll
        for (int j = 0; j < 4; ++j) acc[i][j] = (floatx4){0.f, 0.f, 0.f, 0.f};

    // prologue: tile 0 -> buf 0 (4 loads), tile 1 -> buf 1 (4 loads), in order
    gload_lds16(gA0, &As[0][ld0]); gload_lds16(gA1, &As[0][ld1]);
    gload_lds16(gB0, &Bs[0][ld0]); gload_lds16(gB1, &Bs[0][ld1]);
    gload_lds16(gA0 + 32, &As[1][ld0]); gload_lds16(gA1 + 32, &As[1][ld1]);
    gload_lds16(gB0 + 32, &Bs[1][ld0]); gload_lds16(gB1 + 32, &Bs[1][ld1]);
    gA0 += 64; gA1 += 64; gB0 += 64; gB1 += 64;

    int c = 0, f = 2;
    for (int t = 0; t < NT; ++t) {
        // boundary: tile t's 4 loads landed; tile t+1's 4 stay in flight
        if (t + 1 < NT) asm volatile("s_waitcnt vmcnt(4)" ::: "memory");
        else            asm volatile("s_waitcnt vmcnt(0)" ::: "memory");
        __builtin_amdgcn_s_barrier();

        // ---- phase 0: m-half 0, stage A of tile t+2 ----
        short8 av[4], bv[4];
        #pragma unroll
        for (int y = 0; y < 4; ++y) av[y] = *(const short8*)&As[c][roffA[y]];
        #pragma unroll
        for (int x = 0; x < 4; ++x) bv[x] = *(const short8*)&Bs[c][roffB[x]];
        if (t + 2 < NT) {
            gload_lds16(gA0, &As[f][ld0]);
            gload_lds16(gA1, &As[f][ld1]);
        }
        asm volatile("s_waitcnt lgkmcnt(0)" ::: "memory");  // reads in regs BEFORE barrier
        __builtin_amdgcn_sched_barrier(0);                   // rule #18: pin MFMA below
        __builtin_amdgcn_s_barrier();
        __builtin_amdgcn_s_setprio(1);
        #pragma unroll
        for (int y = 0; y < 4; ++y)
            #pragma unroll
            for (int x = 0; x < 4; ++x)
                acc[y][x] = __builtin_amdgcn_mfma_f32_16x16x32_bf16(av[y], bv[x], acc[y][x], 0, 0, 0);
        __builtin_amdgcn_s_setprio(0);

        // ---- phase 1: m-half 1 (reuse bv), stage B of tile t+2 ----
        short8 aw[4];
        #pragma unroll
        for (int y = 0; y < 4; ++y) aw[y] = *(const short8*)&As[c][2048 + roffA[y]];
        if (t + 2 < NT) {
            gload_lds16(gB0, &Bs[f][ld0]);
            gload_lds16(gB1, &Bs[f][ld1]);
            gA0 += 32; gA1 += 32; gB0 += 32; gB1 += 32;
        }
        asm volatile("s_waitcnt lgkmcnt(0)" ::: "memory");
        __builtin_amdgcn_sched_barrier(0);
        __builtin_amdgcn_s_barrier();
        __builtin_amdgcn_s_setprio(1);
        #pragma unroll
        for (int y = 0; y < 4; ++y)
            #pragma unroll
            for (int x = 0; x < 4; ++x)
                acc[4 + y][x] = __builtin_amdgcn_mfma_f32_16x16x32_bf16(aw[y], bv[x], acc[4 + y][x], 0, 0, 0);
        __builtin_amdgcn_s_setprio(0);

        c = (c == 2) ? 0 : c + 1;
        f = (f == 2) ? 0 : f + 1;
    }

    // ---------- fused loss epilogue ----------
    const int row_base = it * 256 + wr * 128;
    const int col_base = jt * 256 + wc * 64;
    const bool second_half = (jt >= 16);

    #pragma unroll
    for (int fy = 0; fy < 8; ++fy) {
        #pragma unroll
        for (int r = 0; r < 4; ++r) {
            const int row = row_base + fy * 16 + q * 4 + r;
            const float d = diag[row];
            #pragma unroll
            for (int tx = 0; tx < 4; ++tx) {
                const int col = col_base + tx * 16 + cl;
                float v = 0.5f * sims[(size_t)row * N_COLS + col] + 0.5f * acc[fy][tx][r];
                if (second_half && v > d) v = 0.f;
                acc[fy][tx][r] = v * INV_T;
            }
        }
    }

    // i2t row partials over this block's 256 cols
    #pragma unroll
    for (int fy = 0; fy < 8; ++fy) {
        #pragma unroll
        for (int r = 0; r < 4; ++r) {
            float mx = fmaxf(fmaxf(acc[fy][0][r], acc[fy][1][r]),
                             fmaxf(acc[fy][2][r], acc[fy][3][r]));
            #pragma unroll
            for (int off = 1; off < 16; off <<= 1) mx = fmaxf(mx, __shfl_xor(mx, off, 64));
            float sum = 0.f;
            #pragma unroll
            for (int tx = 0; tx < 4; ++tx) sum += __expf(acc[fy][tx][r] - mx);
            #pragma unroll
            for (int off = 1; off < 16; off <<= 1) sum += __shfl_xor(sum, off, 64);
            if (cl == 0) {
                sm_m[wc][wr * 128 + fy * 16 + q * 4 + r] = mx;
                sm_l[wc][wr * 128 + fy * 16 + q * 4 + r] = sum;
            }
        }
    }

    // t2i col partials (first-half cols only) over block's 256 rows
    if (!second_half) {
        #pragma unroll
        for (int tx = 0; tx < 4; ++tx) {
            float mx = -3.4e38f;
            #pragma unroll
            for (int fy = 0; fy < 8; ++fy)
                #pragma unroll
                for (int r = 0; r < 4; ++r) mx = fmaxf(mx, acc[fy][tx][r]);
            mx = fmaxf(mx, __shfl_xor(mx, 16, 64));
            mx = fmaxf(mx, __shfl_xor(mx, 32, 64));
            float sum = 0.f;
            #pragma unroll
            for (int fy = 0; fy < 8; ++fy)
                #pragma unroll
                for (int r = 0; r < 4; ++r) sum += __expf(acc[fy][tx][r] - mx);
            sum += __shfl_xor(sum, 16, 64);
            sum += __shfl_xor(sum, 32, 64);
            if (q == 0) {
                sc_m[wr][wc * 64 + tx * 16 + cl] = mx;
                sc_l[wr][wc * 64 + tx * 16 + cl] = sum;
            }
        }
    }

    __syncthreads();

    if (tid < 256) {
        float m0 = sm_m[0][tid], m1 = sm_m[1][tid], m2 = sm_m[2][tid], m3 = sm_m[3][tid];
        float mm = fmaxf(fmaxf(m0, m1), fmaxf(m2, m3));
        float ll = sm_l[0][tid] * __expf(m0 - mm) + sm_l[1][tid] * __expf(m1 - mm)
                 + sm_l[2][tid] * __expf(m2 - mm) + sm_l[3][tid] * __expf(m3 - mm);
        pi2t_m[(size_t)jt * B_ROWS + it * 256 + tid] = mm;
        pi2t_l[(size_t)jt * B_ROWS + it * 256 + tid] = ll;
    } else if (!second_half) {
        const int t2 = tid - 256;
        float m0 = sc_m[0][t2], m1 = sc_m[1][t2];
        float mm = fmaxf(m0, m1);
        float ll = sc_l[0][t2] * __expf(m0 - mm) + sc_l[1][t2] * __expf(m1 - mm);
        pt2i_m[(size_t)it * B_ROWS + jt * 256 + t2] = mm;
        pt2i_l[(size_t)it * B_ROWS + jt * 256 + t2] = ll;
    }
}

// ---------------------------------------------------------------------------
// Fallback path (fp32 inputs, in-kernel pack) — used if ws too small
// ---------------------------------------------------------------------------
__global__ __launch_bounds__(256) void diag_kernel(
    const float* __restrict__ im, const float* __restrict__ s,
    const float* __restrict__ sims, float* __restrict__ diag)
{
    const int row = blockIdx.x;
    const float4* a = (const float4*)(im + (size_t)row * K_DIM);
    const float4* b = (const float4*)(s  + (size_t)row * K_DIM);
    float sum = 0.f;
    for (int i = threadIdx.x; i < K_DIM / 4; i += 256) {
        float4 x = a[i], y = b[i];
        sum += x.x * y.x + x.y * y.y + x.z * y.z + x.w * y.w;
    }
    #pragma unroll
    for (int off = 1; off < 64; off <<= 1) sum += __shfl_xor(sum, off, 64);
    __shared__ float wsum[4];
    const int lane = threadIdx.x & 63, wid = threadIdx.x >> 6;
    if (lane == 0) wsum[wid] = sum;
    __syncthreads();
    if (threadIdx.x == 0) {
        float tot = wsum[0] + wsum[1] + wsum[2] + wsum[3];
        diag[row] = 0.5f * sims[(size_t)row * N_COLS + row] + 0.5f * tot;
    }
}

__global__ __launch_bounds__(256) void gemm_loss_kernel(
    const float* __restrict__ im, const float* __restrict__ s,
    const float* __restrict__ sims, const float* __restrict__ diag,
    float* __restrict__ pi2t_m, float* __restrict__ pi2t_l,
    float* __restrict__ pt2i_m, float* __restrict__ pt2i_l)
{
    const int jt = blockIdx.x;
    const int it = blockIdx.y;
    const int tid = threadIdx.x;
    const int wid = tid >> 6, lane = tid & 63;
    const int wr = wid >> 1, wc = wid & 1;
    const int q = lane >> 4, cl = lane & 15;

    __shared__ __align__(16) unsigned short Asm[128 * 32];
    __shared__ __align__(16) unsigned short Bsm[128 * 32];
    __shared__ float sm_m[2][128], sm_l[2][128];
    __shared__ float sc_m[2][128], sc_l[2][128];

    const int g0 = tid, g1 = tid + 256;
    const int r0 = g0 >> 2, c0 = (g0 & 3) * 8;
    const int r1 = g1 >> 2, c1 = (g1 & 3) * 8;
    const float* a0 = im + (size_t)(it * 128 + r0) * K_DIM + c0;
    const float* a1 = im + (size_t)(it * 128 + r1) * K_DIM + c1;
    const float* b0 = s  + (size_t)(jt * 128 + r0) * K_DIM + c0;
    const float* b1 = s  + (size_t)(jt * 128 + r1) * K_DIM + c1;
    const int la0 = r0 * 32 + c0, la1 = r1 * 32 + c1;

    floatx4 acc[4][4];
    #pragma unroll
    for (int i = 0; i < 4; ++i)
        #pragma unroll
        for (int j = 0; j < 4; ++j) acc[i][j] = (floatx4){0.f, 0.f, 0.f, 0.f};

    for (int kt = 0; kt < 128; ++kt) {
        float4 xa0 = *(const float4*)a0;
        float4 xa1 = *(const float4*)(a0 + 4);
        float4 ya0 = *(const float4*)a1;
        float4 ya1 = *(const float4*)(a1 + 4);
        float4 xb0 = *(const float4*)b0;
        float4 xb1 = *(const float4*)(b0 + 4);
        float4 yb0 = *(const float4*)b1;
        float4 yb1 = *(const float4*)(b1 + 4);
        a0 += 32; a1 += 32; b0 += 32; b1 += 32;
        __syncthreads();
        *(uint4*)&Asm[la0] = make_uint4(pack2bf16(xa0.x, xa0.y), pack2bf16(xa0.z, xa0.w),
                                        pack2bf16(xa1.x, xa1.y), pack2bf16(xa1.z, xa1.w));
        *(uint4*)&Asm[la1] = make_uint4(pack2bf16(ya0.x, ya0.y), pack2bf16(ya0.z, ya0.w),
                                        pack2bf16(ya1.x, ya1.y), pack2bf16(ya1.z, ya1.w));
        *(uint4*)&Bsm[la0] = make_uint4(pack2bf16(xb0.x, xb0.y), pack2bf16(xb0.z, xb0.w),
                                        pack2bf16(xb1.x, xb1.y), pack2bf16(xb1.z, xb1.w));
        *(uint4*)&Bsm[la1] = make_uint4(pack2bf16(yb0.x, yb0.y), pack2bf16(yb0.z, yb0.w),
                                        pack2bf16(yb1.x, yb1.y), pack2bf16(yb1.z, yb1.w));
        __syncthreads();
        short8 av[4], bv[4];
        #pragma unroll
        for (int ty = 0; ty < 4; ++ty)
            av[ty] = *(const short8*)&Asm[(wr * 64 + ty * 16 + cl) * 32 + q * 8];
        #pragma unroll
        for (int tx = 0; tx < 4; ++tx)
            bv[tx] = *(const short8*)&Bsm[(wc * 64 + tx * 16 + cl) * 32 + q * 8];
        #pragma unroll
        for (int ty = 0; ty < 4; ++ty)
            #pragma unroll
            for (int tx = 0; tx < 4; ++tx)
                acc[ty][tx] = __builtin_amdgcn_mfma_f32_16x16x32_bf16(av[ty], bv[tx], acc[ty][tx], 0, 0, 0);
    }

    const int row_base = it * 128 + wr * 64;
    const int col_base = jt * 128 + wc * 64;
    const bool second_half = (jt >= 32);

    float dv[4][4];
    #pragma unroll
    for (int ty = 0; ty < 4; ++ty)
        #pragma unroll
        for (int r = 0; r < 4; ++r)
            dv[ty][r] = diag[row_base + ty * 16 + q * 4 + r];

    #pragma unroll
    for (int ty = 0; ty < 4; ++ty) {
        #pragma unroll
        for (int tx = 0; tx < 4; ++tx) {
            const int col = col_base + tx * 16 + cl;
            #pragma unroll
            for (int r = 0; r < 4; ++r) {
                const int row = row_base + ty * 16 + q * 4 + r;
                float v = 0.5f * sims[(size_t)row * N_COLS + col] + 0.5f * acc[ty][tx][r];
                if (second_half && v > dv[ty][r]) v = 0.f;
                acc[ty][tx][r] = v * INV_T;
            }
        }
    }

    #pragma unroll
    for (int ty = 0; ty < 4; ++ty) {
        #pragma unroll
        for (int r = 0; r < 4; ++r) {
            float mx = fmaxf(fmaxf(acc[ty][0][r], acc[ty][1][r]),
                             fmaxf(acc[ty][2][r], acc[ty][3][r]));
            #pragma unroll
            for (int off = 1; off < 16; off <<= 1) mx = fmaxf(mx, __shfl_xor(mx, off, 64));
            float sum = 0.f;
            #pragma unroll
            for (int tx = 0; tx < 4; ++tx) sum += __expf(acc[ty][tx][r] - mx);
            #pragma unroll
            for (int off = 1; off < 16; off <<= 1) sum += __shfl_xor(sum, off, 64);
            if (cl == 0) {
                sm_m[wc][wr * 64 + ty * 16 + q * 4 + r] = mx;
                sm_l[wc][wr * 64 + ty * 16 + q * 4 + r] = sum;
            }
        }
    }

    if (!second_half) {
        #pragma unroll
        for (int tx = 0; tx < 4; ++tx) {
            float mx = -3.4e38f;
            #pragma unroll
            for (int ty = 0; ty < 4; ++ty)
                #pragma unroll
                for (int r = 0; r < 4; ++r) mx = fmaxf(mx, acc[ty][tx][r]);
            mx = fmaxf(mx, __shfl_xor(mx, 16, 64));
            mx = fmaxf(mx, __shfl_xor(mx, 32, 64));
            float sum = 0.f;
            #pragma unroll
            for (int ty = 0; ty < 4; ++ty)
                #pragma unroll
                for (int r = 0; r < 4; ++r) sum += __expf(acc[ty][tx][r] - mx);
            sum += __shfl_xor(sum, 16, 64);
            sum += __shfl_xor(sum, 32, 64);
            if (q == 0) {
                sc_m[wr][wc * 64 + tx * 16 + cl] = mx;
                sc_l[wr][wc * 64 + tx * 16 + cl] = sum;
            }
        }
    }

    __syncthreads();

    if (tid < 128) {
        float m0 = sm_m[0][tid], m1 = sm_m[1][tid];
        float mm = fmaxf(m0, m1);
        float ll = sm_l[0][tid] * __expf(m0 - mm) + sm_l[1][tid] * __expf(m1 - mm);
        pi2t_m[(size_t)jt * B_ROWS + it * 128 + tid] = mm;
        pi2t_l[(size_t)jt * B_ROWS + it * 128 + tid] = ll;
    } else if (!second_half) {
        const int t2 = tid - 128;
        float m0 = sc_m[0][t2], m1 = sc_m[1][t2];
        float mm = fmaxf(m0, m1);
        float ll = sc_l[0][t2] * __expf(m0 - mm) + sc_l[1][t2] * __expf(m1 - mm);
        pt2i_m[(size_t)it * B_ROWS + jt * 128 + t2] = mm;
        pt2i_l[(size_t)it * B_ROWS + jt * 128 + t2] = ll;
    }
}

// ---------------------------------------------------------------------------
// K2: merge partials (parameterized tile counts) -> pblk[32]
// ---------------------------------------------------------------------------
__global__ __launch_bounds__(256) void combine_kernel(
    const float* __restrict__ pi2t_m, const float* __restrict__ pi2t_l,
    const float* __restrict__ pt2i_m, const float* __restrict__ pt2i_l,
    const float* __restrict__ diag, float* __restrict__ pblk,
    int nct, int nrt)
{
    const int gid = blockIdx.x * 256 + threadIdx.x;  // 0..8191
    float term;
    if (gid < B_ROWS) {
        const int row = gid;
        float m = pi2t_m[row], l = pi2t_l[row];
        for (int ct = 1; ct < nct; ++ct) {
            float m2 = pi2t_m[(size_t)ct * B_ROWS + row];
            float l2 = pi2t_l[(size_t)ct * B_ROWS + row];
            float nm = fmaxf(m, m2);
            l = l * __expf(m - nm) + l2 * __expf(m2 - nm);
            m = nm;
        }
        term = m + __logf(l) - diag[row] * INV_T;
    } else {
        const int col = gid - B_ROWS;
        float m = pt2i_m[col], l = pt2i_l[col];
        for (int rt = 1; rt < nrt; ++rt) {
            float m2 = pt2i_m[(size_t)rt * B_ROWS + col];
            float l2 = pt2i_l[(size_t)rt * B_ROWS + col];
            float nm = fmaxf(m, m2);
            l = l * __expf(m - nm) + l2 * __expf(m2 - nm);
            m = nm;
        }
        term = m + __logf(l) - diag[col] * INV_T;
    }
    #pragma unroll
    for (int off = 1; off < 64; off <<= 1) term += __shfl_xor(term, off, 64);
    __shared__ float bsum[4];
    if ((threadIdx.x & 63) == 0) bsum[threadIdx.x >> 6] = term;
    __syncthreads();
    if (threadIdx.x == 0) pblk[blockIdx.x] = bsum[0] + bsum[1] + bsum[2] + bsum[3];
}

__global__ void finalize_kernel(const float* __restrict__ pblk, float* __restrict__ out) {
    float v = (threadIdx.x < 32) ? pblk[threadIdx.x] : 0.f;
    #pragma unroll
    for (int off = 1; off < 64; off <<= 1) v += __shfl_xor(v, off, 64);
    if (threadIdx.x == 0) out[0] = v * (1.0f / 4096.0f);
}

extern "C" void kernel_launch(void* const* d_in, const int* in_sizes, int n_in,
                              void* d_out, int out_size, void* d_ws, size_t ws_size,
                              hipStream_t stream)
{
    const float* im   = (const float*)d_in[0];   // [4096, 4096]
    const float* s    = (const float*)d_in[1];   // [8192, 4096]
    const float* sims = (const float*)d_in[2];   // [4096, 8192]
    float* out = (float*)d_out;

    const size_t im_b_bytes = (size_t)B_ROWS * K_DIM * 2;   // 32 MB
    const size_t s_b_bytes  = (size_t)N_COLS * K_DIM * 2;   // 64 MB
    const size_t f32_bytes  = (4096 + 2 * 64 * 4096 + 2 * 32 * 4096 + 32) * sizeof(float);
    const size_t need = im_b_bytes + s_b_bytes + f32_bytes;

    if (ws_size >= need) {
        unsigned short* im_b = (unsigned short*)d_ws;
        unsigned short* s_b  = (unsigned short*)((char*)d_ws + im_b_bytes);
        float* fbase  = (float*)((char*)d_ws + im_b_bytes + s_b_bytes);
        float* diag   = fbase;
        float* pi2t_m = diag + 4096;
        float* pi2t_l = pi2t_m + 64 * 4096;   // carve with fallback-size strides (safe)
        float* pt2i_m = pi2t_l + 64 * 4096;
        float* pt2i_l = pt2i_m + 32 * 4096;
        float* pblk   = pt2i_l + 32 * 4096;

        convert_diag_kernel<<<N_COLS, 256, 0, stream>>>(im, s, sims, im_b, s_b, diag);
        gemm_loss_256_kernel<<<512, 512, 0, stream>>>(im_b, s_b, sims, diag,
                                                      pi2t_m, pi2t_l, pt2i_m, pt2i_l);
        combine_kernel<<<32, 256, 0, stream>>>(pi2t_m, pi2t_l, pt2i_m, pt2i_l, diag, pblk, 32, 16);
        finalize_kernel<<<1, 64, 0, stream>>>(pblk, out);
    } else {
        float* ws = (float*)d_ws;
        float* diag   = ws;
        float* pi2t_m = diag + 4096;
        float* pi2t_l = pi2t_m + 64 * 4096;
        float* pt2i_m = pi2t_l + 64 * 4096;
        float* pt2i_l = pt2i_m + 32 * 4096;
        float* pblk   = pt2i_l + 32 * 4096;

        diag_kernel<<<4096, 256, 0, stream>>>(im, s, sims, diag);
        gemm_loss_kernel<<<dim3(64, 32), 256, 0, stream>>>(im, s, sims, diag,
                                                           pi2t_m, pi2t_l, pt2i_m, pt2i_l);
        combine_kernel<<<32, 256, 0, stream>>>(pi2t_m, pi2t_l, pt2i_m, pt2i_l, diag, pblk, 64, 32);
        finalize_kernel<<<1, 64, 0, stream>>>(pblk, out);
    }
}

// Round 4
// 683.038 us; speedup vs baseline: 1.0938x; 1.0938x over previous
//
#include <hip/hip_runtime.h>
#include <hip/hip_bf16.h>

typedef __attribute__((ext_vector_type(8))) short short8;
typedef __attribute__((ext_vector_type(4))) float floatx4;

#define B_ROWS 4096
#define N_COLS 8192
#define K_DIM  4096
#define INV_T  10.0f

// round-half-up fp32 -> bf16 pair pack
__device__ __forceinline__ unsigned pack2bf16(float a, float b) {
    unsigned lo = (__float_as_uint(a) + 0x8000u) >> 16;
    unsigned hi = (__float_as_uint(b) + 0x8000u) & 0xFFFF0000u;
    return lo | hi;
}

// async global->LDS, 16B per lane, LDS dest = wave-uniform base + lane*16
__device__ __forceinline__ void gload_lds16(const void* g, void* l) {
    __builtin_amdgcn_global_load_lds(
        (const __attribute__((address_space(1))) void*)g,
        (__attribute__((address_space(3))) void*)l,
        16, 0, 0);
}

// ---------------------------------------------------------------------------
// K0: convert im,s -> bf16 in ws; fused diag computation. (unchanged)
// ---------------------------------------------------------------------------
__global__ __launch_bounds__(256) void convert_diag_kernel(
    const float* __restrict__ im, const float* __restrict__ s,
    const float* __restrict__ sims,
    unsigned short* __restrict__ im_b, unsigned short* __restrict__ s_b,
    float* __restrict__ diag)
{
    const int row = blockIdx.x;                       // 0..8191
    const float4* srow = (const float4*)(s + (size_t)row * K_DIM);
    uint4* sb = (uint4*)(s_b + (size_t)row * K_DIM);
    const bool has_im = row < B_ROWS;
    const float4* arow = (const float4*)(im + (size_t)row * K_DIM);
    uint4* ab = (uint4*)(im_b + (size_t)row * K_DIM);

    float sum = 0.f;
    for (int i = threadIdx.x; i < K_DIM / 8; i += 256) {
        float4 y0 = srow[2 * i], y1 = srow[2 * i + 1];
        sb[i] = make_uint4(pack2bf16(y0.x, y0.y), pack2bf16(y0.z, y0.w),
                           pack2bf16(y1.x, y1.y), pack2bf16(y1.z, y1.w));
        if (has_im) {
            float4 x0 = arow[2 * i], x1 = arow[2 * i + 1];
            ab[i] = make_uint4(pack2bf16(x0.x, x0.y), pack2bf16(x0.z, x0.w),
                               pack2bf16(x1.x, x1.y), pack2bf16(x1.z, x1.w));
            sum += x0.x * y0.x + x0.y * y0.y + x0.z * y0.z + x0.w * y0.w;
            sum += x1.x * y1.x + x1.y * y1.y + x1.z * y1.z + x1.w * y1.w;
        }
    }
    if (has_im) {
        #pragma unroll
        for (int off = 1; off < 64; off <<= 1) sum += __shfl_xor(sum, off, 64);
        __shared__ float wsum[4];
        const int lane = threadIdx.x & 63, wid = threadIdx.x >> 6;
        if (lane == 0) wsum[wid] = sum;
        __syncthreads();
        if (threadIdx.x == 0) {
            float tot = wsum[0] + wsum[1] + wsum[2] + wsum[3];
            diag[row] = 0.5f * sims[(size_t)row * N_COLS + row] + 0.5f * tot;
        }
    }
}

// ---------------------------------------------------------------------------
// K1: 256x256 tile, 8-phase counted-vmcnt schedule (m201 port), BK=64.
//
// LDS: staging units [dbuf][khalf] of [256 rows][32 k] bf16 = 16 KB each;
//   A: 2x2 units (64 KB) + B: 2x2 (64 KB) = 128 KB. Even K-steps -> dbuf0,
//   odd -> dbuf1 (compile-time buffer indices). Epilogue arrays alias As.
//
// Iteration i computes K-steps s0=2i (dbuf0, phases 1-4) and s1=2i+1
// (dbuf1, phases 5-8). Phase = (khalf ks, M-quadrant Q): 8/4 ds_read_b128 +
// one staged unit (2 gloads) + barrier + lgkmcnt(0) + 16 MFMA + barrier.
// Stage targets the unit freed at the end of the previous phase:
//   ph1: A,B k1(s1)->dbuf1   ph3: A k0(2i+2)->dbuf0   ph4: B k0(2i+2)
//   ph5: A k1(2i+2)          ph6: B k1(2i+2)
//   ph7: A k0(2i+3)->dbuf1   ph8: B k0(2i+3)
// vmcnt(4) ONLY at ph4 (covers s1-k1 for ph7) and ph8 (covers 2i+2 for
// next ph1/ph3); never 0 in steady state (T4). Last iter: ph4 -> vmcnt(0).
//
// Swizzle (verified, conflict-free): unit rows are 64B; slot' = slot ^
// ((row>>1)&3); staging pre-swizzles the GLOBAL per-lane address (skel),
// LDS dest stays linear; read adds swz = (lq ^ ((cl>>1)&3))*8.
//
// Block->tile mapping: round-3 XCD-compact 8it x 4jt (FETCH 359 MB, keep).
// ---------------------------------------------------------------------------
#define STAGE_A(d, ks, s) do { \
    gload_lds16(gA + (size_t)(s) * 64 + (ks) * 32, &As[d][ks][ldw]); \
    gload_lds16(gA + (size_t)128 * K_DIM + (size_t)(s) * 64 + (ks) * 32, &As[d][ks][4096 + ldw]); \
} while (0)
#define STAGE_B(d, ks, s) do { \
    gload_lds16(gB + (size_t)(s) * 64 + (ks) * 32, &Bs[d][ks][ldw]); \
    gload_lds16(gB + (size_t)128 * K_DIM + (size_t)(s) * 64 + (ks) * 32, &Bs[d][ks][4096 + ldw]); \
} while (0)
#define LOAD_AV(d, ks, qoff) do { \
    _Pragma("unroll") \
    for (int y = 0; y < 4; ++y) av[y] = *(const short8*)&As[d][ks][(qoff) + roffA[y]]; \
} while (0)
#define LOAD_BV(d, ks) do { \
    _Pragma("unroll") \
    for (int x = 0; x < 4; ++x) bv[x] = *(const short8*)&Bs[d][ks][roffB[x]]; \
} while (0)
#define SYNC_MFMA(FY0) do { \
    __builtin_amdgcn_s_barrier(); \
    asm volatile("s_waitcnt lgkmcnt(0)" ::: "memory"); \
    __builtin_amdgcn_sched_barrier(0); \
    __builtin_amdgcn_s_setprio(1); \
    _Pragma("unroll") \
    for (int y = 0; y < 4; ++y) \
        _Pragma("unroll") \
        for (int x = 0; x < 4; ++x) \
            acc[(FY0) + y][x] = __builtin_amdgcn_mfma_f32_16x16x32_bf16(av[y], bv[x], acc[(FY0) + y][x], 0, 0, 0); \
    __builtin_amdgcn_s_setprio(0); \
    __builtin_amdgcn_s_barrier(); \
} while (0)

__global__ __launch_bounds__(512, 2) void gemm_loss_256_kernel(
    const unsigned short* __restrict__ im_b, const unsigned short* __restrict__ s_b,
    const float* __restrict__ sims, const float* __restrict__ diag,
    float* __restrict__ pi2t_m, float* __restrict__ pi2t_l,
    float* __restrict__ pt2i_m, float* __restrict__ pt2i_l)
{
    const int bid  = blockIdx.x;
    const int half = bid >> 8;           // 0: jt 0..15, 1: jt 16..31
    const int xcd  = bid & 7;            // round-robin dispatch => XCD id
    const int l    = (bid >> 3) & 31;    // 32 blocks per XCD per half
    const int it   = (xcd >> 2) * 8 + (l & 7);             // 0..15
    const int jt   = half * 16 + (xcd & 3) * 4 + (l >> 3); // 0..31
    const int tid = threadIdx.x;
    const int wid = tid >> 6, lane = tid & 63;
    const int wr = wid >> 2, wc = wid & 3;         // wave grid 2 x 4
    const int lq = lane >> 4, cl = lane & 15;

    __shared__ __align__(16) unsigned short As[2][2][8192];  // 64 KB [dbuf][khalf]
    __shared__ __align__(16) unsigned short Bs[2][2][8192];  // 64 KB
    // epilogue arrays alias As (staging dead, all gloads drained by then)
    float* sm_m = (float*)&As[0][0][0];        // [4][256]
    float* sm_l = sm_m + 4 * 256;              // [4][256]
    float* sc_m = sm_l + 4 * 256;              // [2][256]
    float* sc_l = sc_m + 2 * 256;              // [2][256]

    // staging: thread covers row srow (+128 on 2nd call), 16B at swizzled k
    const int srow = tid >> 2;
    const int skel = ((tid & 3) ^ ((tid >> 3) & 3)) * 8;
    const unsigned short* gA = im_b + (size_t)(it * 256 + srow) * K_DIM + skel;
    const unsigned short* gB = s_b  + (size_t)(jt * 256 + srow) * K_DIM + skel;
    const int ldw = wid * 512;   // wave-uniform LDS element offset per call

    // read-side swizzled fragment offsets (elements within a unit)
    const int swz = (lq ^ ((cl >> 1) & 3)) * 8;
    int roffA[4], roffB[4];
    #pragma unroll
    for (int t = 0; t < 4; ++t) {
        roffA[t] = (wr * 128 + t * 16 + cl) * 32 + swz;
        roffB[t] = (wc * 64  + t * 16 + cl) * 32 + swz;
    }

    floatx4 acc[8][4];
    #pragma unroll
    for (int i = 0; i < 8; ++i)
        #pragma unroll
        for (int j = 0; j < 4; ++j) acc[i][j] = (floatx4){0.f, 0.f, 0.f, 0.f};

    // prologue: s0=0 fully (dbuf0), s1=1 k0 units (dbuf1) = 12 loads
    STAGE_A(0, 0, 0); STAGE_B(0, 0, 0);
    STAGE_A(0, 1, 0); STAGE_B(0, 1, 0);
    STAGE_A(1, 0, 1); STAGE_B(1, 0, 1);
    asm volatile("s_waitcnt vmcnt(4)" ::: "memory");   // s0 landed; s1-k0 in flight
    __builtin_amdgcn_s_barrier();

    for (int i = 0; i < 32; ++i) {
        const bool last = (i == 31);
        const int s1 = 2 * i + 1, s2 = 2 * i + 2, s3 = 2 * i + 3;
        short8 av[4], bv[4];

        // ph1: (dbuf0, k0, Q0) | stage s1 k1 -> dbuf1
        LOAD_AV(0, 0, 0); LOAD_BV(0, 0);
        STAGE_A(1, 1, s1); STAGE_B(1, 1, s1);
        SYNC_MFMA(0);

        // ph2: (dbuf0, k0, Q1)
        LOAD_AV(0, 0, 2048);
        SYNC_MFMA(4);

        // ph3: (dbuf0, k1, Q0) | stage s2 k0 A -> dbuf0 (freed ph2)
        LOAD_AV(0, 1, 0); LOAD_BV(0, 1);
        if (!last) STAGE_A(0, 0, s2);
        SYNC_MFMA(0);

        // ph4: (dbuf0, k1, Q1) | stage s2 k0 B | counted wait
        LOAD_AV(0, 1, 2048);
        if (!last) STAGE_B(0, 0, s2);
        if (last) asm volatile("s_waitcnt vmcnt(0)" ::: "memory");
        else      asm volatile("s_waitcnt vmcnt(4)" ::: "memory");
        SYNC_MFMA(4);

        // ph5: (dbuf1, k0, Q0) | stage s2 k1 A (freed ph4)
        LOAD_AV(1, 0, 0); LOAD_BV(1, 0);
        if (!last) STAGE_A(0, 1, s2);
        SYNC_MFMA(0);

        // ph6: (dbuf1, k0, Q1) | stage s2 k1 B
        LOAD_AV(1, 0, 2048);
        if (!last) STAGE_B(0, 1, s2);
        SYNC_MFMA(4);

        // ph7: (dbuf1, k1, Q0) | stage s3 k0 A -> dbuf1 (freed ph6)
        LOAD_AV(1, 1, 0); LOAD_BV(1, 1);
        if (!last) STAGE_A(1, 0, s3);
        SYNC_MFMA(0);

        // ph8: (dbuf1, k1, Q1) | stage s3 k0 B | counted wait
        LOAD_AV(1, 1, 2048);
        if (!last) {
            STAGE_B(1, 0, s3);
            asm volatile("s_waitcnt vmcnt(4)" ::: "memory");
        }
        SYNC_MFMA(4);
    }

    // ---------- fused loss epilogue (unchanged; arrays alias As) ----------
    const int q = lq;
    const int row_base = it * 256 + wr * 128;
    const int col_base = jt * 256 + wc * 64;
    const bool second_half = (jt >= 16);

    #pragma unroll
    for (int fy = 0; fy < 8; ++fy) {
        #pragma unroll
        for (int r = 0; r < 4; ++r) {
            const int row = row_base + fy * 16 + q * 4 + r;
            const float d = diag[row];
            #pragma unroll
            for (int tx = 0; tx < 4; ++tx) {
                const int col = col_base + tx * 16 + cl;
                float v = 0.5f * sims[(size_t)row * N_COLS + col] + 0.5f * acc[fy][tx][r];
                if (second_half && v > d) v = 0.f;
                acc[fy][tx][r] = v * INV_T;
            }
        }
    }

    // i2t row partials over this block's 256 cols
    #pragma unroll
    for (int fy = 0; fy < 8; ++fy) {
        #pragma unroll
        for (int r = 0; r < 4; ++r) {
            float mx = fmaxf(fmaxf(acc[fy][0][r], acc[fy][1][r]),
                             fmaxf(acc[fy][2][r], acc[fy][3][r]));
            #pragma unroll
            for (int off = 1; off < 16; off <<= 1) mx = fmaxf(mx, __shfl_xor(mx, off, 64));
            float sum = 0.f;
            #pragma unroll
            for (int tx = 0; tx < 4; ++tx) sum += __expf(acc[fy][tx][r] - mx);
            #pragma unroll
            for (int off = 1; off < 16; off <<= 1) sum += __shfl_xor(sum, off, 64);
            if (cl == 0) {
                sm_m[wc * 256 + wr * 128 + fy * 16 + q * 4 + r] = mx;
                sm_l[wc * 256 + wr * 128 + fy * 16 + q * 4 + r] = sum;
            }
        }
    }

    // t2i col partials (first-half cols only) over block's 256 rows
    if (!second_half) {
        #pragma unroll
        for (int tx = 0; tx < 4; ++tx) {
            float mx = -3.4e38f;
            #pragma unroll
            for (int fy = 0; fy < 8; ++fy)
                #pragma unroll
                for (int r = 0; r < 4; ++r) mx = fmaxf(mx, acc[fy][tx][r]);
            mx = fmaxf(mx, __shfl_xor(mx, 16, 64));
            mx = fmaxf(mx, __shfl_xor(mx, 32, 64));
            float sum = 0.f;
            #pragma unroll
            for (int fy = 0; fy < 8; ++fy)
                #pragma unroll
                for (int r = 0; r < 4; ++r) sum += __expf(acc[fy][tx][r] - mx);
            sum += __shfl_xor(sum, 16, 64);
            sum += __shfl_xor(sum, 32, 64);
            if (q == 0) {
                sc_m[wr * 256 + wc * 64 + tx * 16 + cl] = mx;
                sc_l[wr * 256 + wc * 64 + tx * 16 + cl] = sum;
            }
        }
    }

    __syncthreads();

    if (tid < 256) {
        float m0 = sm_m[tid], m1 = sm_m[256 + tid], m2 = sm_m[512 + tid], m3 = sm_m[768 + tid];
        float mm = fmaxf(fmaxf(m0, m1), fmaxf(m2, m3));
        float ll = sm_l[tid] * __expf(m0 - mm) + sm_l[256 + tid] * __expf(m1 - mm)
                 + sm_l[512 + tid] * __expf(m2 - mm) + sm_l[768 + tid] * __expf(m3 - mm);
        pi2t_m[(size_t)jt * B_ROWS + it * 256 + tid] = mm;
        pi2t_l[(size_t)jt * B_ROWS + it * 256 + tid] = ll;
    } else if (!second_half) {
        const int t2 = tid - 256;
        float m0 = sc_m[t2], m1 = sc_m[256 + t2];
        float mm = fmaxf(m0, m1);
        float ll = sc_l[t2] * __expf(m0 - mm) + sc_l[256 + t2] * __expf(m1 - mm);
        pt2i_m[(size_t)it * B_ROWS + jt * 256 + t2] = mm;
        pt2i_l[(size_t)it * B_ROWS + jt * 256 + t2] = ll;
    }
}

// ---------------------------------------------------------------------------
// Fallback path (fp32 inputs, in-kernel pack) — used if ws too small
// ---------------------------------------------------------------------------
__global__ __launch_bounds__(256) void diag_kernel(
    const float* __restrict__ im, const float* __restrict__ s,
    const float* __restrict__ sims, float* __restrict__ diag)
{
    const int row = blockIdx.x;
    const float4* a = (const float4*)(im + (size_t)row * K_DIM);
    const float4* b = (const float4*)(s  + (size_t)row * K_DIM);
    float sum = 0.f;
    for (int i = threadIdx.x; i < K_DIM / 4; i += 256) {
        float4 x = a[i], y = b[i];
        sum += x.x * y.x + x.y * y.y + x.z * y.z + x.w * y.w;
    }
    #pragma unroll
    for (int off = 1; off < 64; off <<= 1) sum += __shfl_xor(sum, off, 64);
    __shared__ float wsum[4];
    const int lane = threadIdx.x & 63, wid = threadIdx.x >> 6;
    if (lane == 0) wsum[wid] = sum;
    __syncthreads();
    if (threadIdx.x == 0) {
        float tot = wsum[0] + wsum[1] + wsum[2] + wsum[3];
        diag[row] = 0.5f * sims[(size_t)row * N_COLS + row] + 0.5f * tot;
    }
}

__global__ __launch_bounds__(256) void gemm_loss_kernel(
    const float* __restrict__ im, const float* __restrict__ s,
    const float* __restrict__ sims, const float* __restrict__ diag,
    float* __restrict__ pi2t_m, float* __restrict__ pi2t_l,
    float* __restrict__ pt2i_m, float* __restrict__ pt2i_l)
{
    const int jt = blockIdx.x;
    const int it = blockIdx.y;
    const int tid = threadIdx.x;
    const int wid = tid >> 6, lane = tid & 63;
    const int wr = wid >> 1, wc = wid & 1;
    const int q = lane >> 4, cl = lane & 15;

    __shared__ __align__(16) unsigned short Asm[128 * 32];
    __shared__ __align__(16) unsigned short Bsm[128 * 32];
    __shared__ float sm_m[2][128], sm_l[2][128];
    __shared__ float sc_m[2][128], sc_l[2][128];

    const int g0 = tid, g1 = tid + 256;
    const int r0 = g0 >> 2, c0 = (g0 & 3) * 8;
    const int r1 = g1 >> 2, c1 = (g1 & 3) * 8;
    const float* a0 = im + (size_t)(it * 128 + r0) * K_DIM + c0;
    const float* a1 = im + (size_t)(it * 128 + r1) * K_DIM + c1;
    const float* b0 = s  + (size_t)(jt * 128 + r0) * K_DIM + c0;
    const float* b1 = s  + (size_t)(jt * 128 + r1) * K_DIM + c1;
    const int la0 = r0 * 32 + c0, la1 = r1 * 32 + c1;

    floatx4 acc[4][4];
    #pragma unroll
    for (int i = 0; i < 4; ++i)
        #pragma unroll
        for (int j = 0; j < 4; ++j) acc[i][j] = (floatx4){0.f, 0.f, 0.f, 0.f};

    for (int kt = 0; kt < 128; ++kt) {
        float4 xa0 = *(const float4*)a0;
        float4 xa1 = *(const float4*)(a0 + 4);
        float4 ya0 = *(const float4*)a1;
        float4 ya1 = *(const float4*)(a1 + 4);
        float4 xb0 = *(const float4*)b0;
        float4 xb1 = *(const float4*)(b0 + 4);
        float4 yb0 = *(const float4*)b1;
        float4 yb1 = *(const float4*)(b1 + 4);
        a0 += 32; a1 += 32; b0 += 32; b1 += 32;
        __syncthreads();
        *(uint4*)&Asm[la0] = make_uint4(pack2bf16(xa0.x, xa0.y), pack2bf16(xa0.z, xa0.w),
                                        pack2bf16(xa1.x, xa1.y), pack2bf16(xa1.z, xa1.w));
        *(uint4*)&Asm[la1] = make_uint4(pack2bf16(ya0.x, ya0.y), pack2bf16(ya0.z, ya0.w),
                                        pack2bf16(ya1.x, ya1.y), pack2bf16(ya1.z, ya1.w));
        *(uint4*)&Bsm[la0] = make_uint4(pack2bf16(xb0.x, xb0.y), pack2bf16(xb0.z, xb0.w),
                                        pack2bf16(xb1.x, xb1.y), pack2bf16(xb1.z, xb1.w));
        *(uint4*)&Bsm[la1] = make_uint4(pack2bf16(yb0.x, yb0.y), pack2bf16(yb0.z, yb0.w),
                                        pack2bf16(yb1.x, yb1.y), pack2bf16(yb1.z, yb1.w));
        __syncthreads();
        short8 av[4], bv[4];
        #pragma unroll
        for (int ty = 0; ty < 4; ++ty)
            av[ty] = *(const short8*)&Asm[(wr * 64 + ty * 16 + cl) * 32 + q * 8];
        #pragma unroll
        for (int tx = 0; tx < 4; ++tx)
            bv[tx] = *(const short8*)&Bsm[(wc * 64 + tx * 16 + cl) * 32 + q * 8];
        #pragma unroll
        for (int ty = 0; ty < 4; ++ty)
            #pragma unroll
            for (int tx = 0; tx < 4; ++tx)
                acc[ty][tx] = __builtin_amdgcn_mfma_f32_16x16x32_bf16(av[ty], bv[tx], acc[ty][tx], 0, 0, 0);
    }

    const int row_base = it * 128 + wr * 64;
    const int col_base = jt * 128 + wc * 64;
    const bool second_half = (jt >= 32);

    float dv[4][4];
    #pragma unroll
    for (int ty = 0; ty < 4; ++ty)
        #pragma unroll
        for (int r = 0; r < 4; ++r)
            dv[ty][r] = diag[row_base + ty * 16 + q * 4 + r];

    #pragma unroll
    for (int ty = 0; ty < 4; ++ty) {
        #pragma unroll
        for (int tx = 0; tx < 4; ++tx) {
            const int col = col_base + tx * 16 + cl;
            #pragma unroll
            for (int r = 0; r < 4; ++r) {
                const int row = row_base + ty * 16 + q * 4 + r;
                float v = 0.5f * sims[(size_t)row * N_COLS + col] + 0.5f * acc[ty][tx][r];
                if (second_half && v > dv[ty][r]) v = 0.f;
                acc[ty][tx][r] = v * INV_T;
            }
        }
    }

    #pragma unroll
    for (int ty = 0; ty < 4; ++ty) {
        #pragma unroll
        for (int r = 0; r < 4; ++r) {
            float mx = fmaxf(fmaxf(acc[ty][0][r], acc[ty][1][r]),
                             fmaxf(acc[ty][2][r], acc[ty][3][r]));
            #pragma unroll
            for (int off = 1; off < 16; off <<= 1) mx = fmaxf(mx, __shfl_xor(mx, off, 64));
            float sum = 0.f;
            #pragma unroll
            for (int tx = 0; tx < 4; ++tx) sum += __expf(acc[ty][tx][r] - mx);
            #pragma unroll
            for (int off = 1; off < 16; off <<= 1) sum += __shfl_xor(sum, off, 64);
            if (cl == 0) {
                sm_m[wc][wr * 64 + ty * 16 + q * 4 + r] = mx;
                sm_l[wc][wr * 64 + ty * 16 + q * 4 + r] = sum;
            }
        }
    }

    if (!second_half) {
        #pragma unroll
        for (int tx = 0; tx < 4; ++tx) {
            float mx = -3.4e38f;
            #pragma unroll
            for (int ty = 0; ty < 4; ++ty)
                #pragma unroll
                for (int r = 0; r < 4; ++r) mx = fmaxf(mx, acc[ty][tx][r]);
            mx = fmaxf(mx, __shfl_xor(mx, 16, 64));
            mx = fmaxf(mx, __shfl_xor(mx, 32, 64));
            float sum = 0.f;
            #pragma unroll
            for (int ty = 0; ty < 4; ++ty)
                #pragma unroll
                for (int r = 0; r < 4; ++r) sum += __expf(acc[ty][tx][r] - mx);
            sum += __shfl_xor(sum, 16, 64);
            sum += __shfl_xor(sum, 32, 64);
            if (q == 0) {
                sc_m[wr][wc * 64 + tx * 16 + cl] = mx;
                sc_l[wr][wc * 64 + tx * 16 + cl] = sum;
            }
        }
    }

    __syncthreads();

    if (tid < 128) {
        float m0 = sm_m[0][tid], m1 = sm_m[1][tid];
        float mm = fmaxf(m0, m1);
        float ll = sm_l[0][tid] * __expf(m0 - mm) + sm_l[1][tid] * __expf(m1 - mm);
        pi2t_m[(size_t)jt * B_ROWS + it * 128 + tid] = mm;
        pi2t_l[(size_t)jt * B_ROWS + it * 128 + tid] = ll;
    } else if (!second_half) {
        const int t2 = tid - 128;
        float m0 = sc_m[0][t2], m1 = sc_m[1][t2];
        float mm = fmaxf(m0, m1);
        float ll = sc_l[0][t2] * __expf(m0 - mm) + sc_l[1][t2] * __expf(m1 - mm);
        pt2i_m[(size_t)it * B_ROWS + jt * 128 + t2] = mm;
        pt2i_l[(size_t)it * B_ROWS + jt * 128 + t2] = ll;
    }
}

// ---------------------------------------------------------------------------
// K2: merge partials (parameterized tile counts) -> pblk[32]
// ---------------------------------------------------------------------------
__global__ __launch_bounds__(256) void combine_kernel(
    const float* __restrict__ pi2t_m, const float* __restrict__ pi2t_l,
    const float* __restrict__ pt2i_m, const float* __restrict__ pt2i_l,
    const float* __restrict__ diag, float* __restrict__ pblk,
    int nct, int nrt)
{
    const int gid = blockIdx.x * 256 + threadIdx.x;  // 0..8191
    float term;
    if (gid < B_ROWS) {
        const int row = gid;
        float m = pi2t_m[row], l = pi2t_l[row];
        for (int ct = 1; ct < nct; ++ct) {
            float m2 = pi2t_m[(size_t)ct * B_ROWS + row];
            float l2 = pi2t_l[(size_t)ct * B_ROWS + row];
            float nm = fmaxf(m, m2);
            l = l * __expf(m - nm) + l2 * __expf(m2 - nm);
            m = nm;
        }
        term = m + __logf(l) - diag[row] * INV_T;
    } else {
        const int col = gid - B_ROWS;
        float m = pt2i_m[col], l = pt2i_l[col];
        for (int rt = 1; rt < nrt; ++rt) {
            float m2 = pt2i_m[(size_t)rt * B_ROWS + col];
            float l2 = pt2i_l[(size_t)rt * B_ROWS + col];
            float nm = fmaxf(m, m2);
            l = l * __expf(m - nm) + l2 * __expf(m2 - nm);
            m = nm;
        }
        term = m + __logf(l) - diag[col] * INV_T;
    }
    #pragma unroll
    for (int off = 1; off < 64; off <<= 1) term += __shfl_xor(term, off, 64);
    __shared__ float bsum[4];
    if ((threadIdx.x & 63) == 0) bsum[threadIdx.x >> 6] = term;
    __syncthreads();
    if (threadIdx.x == 0) pblk[blockIdx.x] = bsum[0] + bsum[1] + bsum[2] + bsum[3];
}

__global__ void finalize_kernel(const float* __restrict__ pblk, float* __restrict__ out) {
    float v = (threadIdx.x < 32) ? pblk[threadIdx.x] : 0.f;
    #pragma unroll
    for (int off = 1; off < 64; off <<= 1) v += __shfl_xor(v, off, 64);
    if (threadIdx.x == 0) out[0] = v * (1.0f / 4096.0f);
}

extern "C" void kernel_launch(void* const* d_in, const int* in_sizes, int n_in,
                              void* d_out, int out_size, void* d_ws, size_t ws_size,
                              hipStream_t stream)
{
    const float* im   = (const float*)d_in[0];   // [4096, 4096]
    const float* s    = (const float*)d_in[1];   // [8192, 4096]
    const float* sims = (const float*)d_in[2];   // [4096, 8192]
    float* out = (float*)d_out;

    const size_t im_b_bytes = (size_t)B_ROWS * K_DIM * 2;   // 32 MB
    const size_t s_b_bytes  = (size_t)N_COLS * K_DIM * 2;   // 64 MB
    const size_t f32_bytes  = (4096 + 2 * 64 * 4096 + 2 * 32 * 4096 + 32) * sizeof(float);
    const size_t need = im_b_bytes + s_b_bytes + f32_bytes;

    if (ws_size >= need) {
        unsigned short* im_b = (unsigned short*)d_ws;
        unsigned short* s_b  = (unsigned short*)((char*)d_ws + im_b_bytes);
        float* fbase  = (float*)((char*)d_ws + im_b_bytes + s_b_bytes);
        float* diag   = fbase;
        float* pi2t_m = diag + 4096;
        float* pi2t_l = pi2t_m + 64 * 4096;   // carve with fallback-size strides (safe)
        float* pt2i_m = pi2t_l + 64 * 4096;
        float* pt2i_l = pt2i_m + 32 * 4096;
        float* pblk   = pt2i_l + 32 * 4096;

        convert_diag_kernel<<<N_COLS, 256, 0, stream>>>(im, s, sims, im_b, s_b, diag);
        gemm_loss_256_kernel<<<512, 512, 0, stream>>>(im_b, s_b, sims, diag,
                                                      pi2t_m, pi2t_l, pt2i_m, pt2i_l);
        combine_kernel<<<32, 256, 0, stream>>>(pi2t_m, pi2t_l, pt2i_m, pt2i_l, diag, pblk, 32, 16);
        finalize_kernel<<<1, 64, 0, stream>>>(pblk, out);
    } else {
        float* ws = (float*)d_ws;
        float* diag   = ws;
        float* pi2t_m = diag + 4096;
        float* pi2t_l = pi2t_m + 64 * 4096;
        float* pt2i_m = pi2t_l + 64 * 4096;
        float* pt2i_l = pt2i_m + 32 * 4096;
        float* pblk   = pt2i_l + 32 * 4096;

        diag_kernel<<<4096, 256, 0, stream>>>(im, s, sims, diag);
        gemm_loss_kernel<<<dim3(64, 32), 256, 0, stream>>>(im, s, sims, diag,
                                                           pi2t_m, pi2t_l, pt2i_m, pt2i_l);
        combine_kernel<<<32, 256, 0, stream>>>(pi2t_m, pi2t_l, pt2i_m, pt2i_l, diag, pblk, 64, 32);
        finalize_kernel<<<1, 64, 0, stream>>>(pblk, out);
    }
}